// Round 15
// baseline (1119.727 us; speedup 1.0000x reference)
//
#include <hip/hip_runtime.h>
#include <hip/hip_bf16.h>
#include <math.h>

#define N_DOC 4
#define C_    1024
#define D_    768
#define H_    12
#define E_    40
#define M_    3
#define P_    800
#define NP_   3200
#define EMB_  768
#define NREL_ 97
#define IN2_  1536   // 2*D

#define GLOAD_LDS16(g, l) \
  __builtin_amdgcn_global_load_lds( \
      (const __attribute__((address_space(1))) void*)(g), \
      (__attribute__((address_space(3))) void*)(l), 16, 0, 0)

// ---------------------------------------------------------------- A: ent_emb
__global__ void k_ent_emb(const float* __restrict__ seq, const int* __restrict__ mpos,
                          float* __restrict__ ent_emb) {
  int ne = blockIdx.x;                 // 0..159
  int n = ne / E_, e = ne % E_;
  int base = (n * E_ + e) * M_;
  int p0 = mpos[base + 0] + 1, p1 = mpos[base + 1] + 1, p2 = mpos[base + 2] + 1;
  const float* s0 = seq + ((size_t)n * C_ + p0) * D_;
  const float* s1 = seq + ((size_t)n * C_ + p1) * D_;
  const float* s2 = seq + ((size_t)n * C_ + p2) * D_;
  float* out = ent_emb + (size_t)ne * D_;
  for (int d = threadIdx.x; d < D_; d += blockDim.x) {
    double a = s0[d], b = s1[d], c = s2[d];
    double mx = fmax(a, fmax(b, c));
    double s = exp(a - mx) + exp(b - mx) + exp(c - mx);
    out[d] = (float)(mx + log(s));
  }
}

// ---------------------------------------------------------------- B: ent_att
__global__ void k_ent_att(const float* __restrict__ att, const int* __restrict__ mpos,
                          float* __restrict__ ent_att) {
  int idx = blockIdx.x * 256 + threadIdx.x;        // exactly N*E*H*C = 1966080
  int c = idx & (C_ - 1);
  int h = (idx >> 10) % H_;
  int rem = idx / (C_ * H_);
  int e = rem % E_;
  int n = rem / E_;
  int base = (n * E_ + e) * M_;
  float acc = 0.f;
#pragma unroll
  for (int m = 0; m < M_; ++m) {
    int p = mpos[base + m] + 1;
    acc += att[(((size_t)n * H_ + h) * C_ + p) * C_ + c];
  }
  ent_att[idx] = acc / 3.0f;
}

// ---------------------------------------------------------------- C: ht_att
__global__ void k_ht_att(const float* __restrict__ ent_att, const int* __restrict__ hts,
                         float* __restrict__ ht) {
  int np = blockIdx.x;                 // 0..3199
  int n = np / P_;
  int hi = hts[np * 2 + 0], ti = hts[np * 2 + 1];
  const float* ea_h = ent_att + (size_t)(n * E_ + hi) * H_ * C_;
  const float* ea_t = ent_att + (size_t)(n * E_ + ti) * H_ * C_;
  const int t = threadIdx.x;           // 0..63
  float4 v[4];
  float local = 0.f;
#pragma unroll
  for (int q = 0; q < 4; ++q) {
    int c = t * 4 + 256 * q;
    float4 a = {0.f, 0.f, 0.f, 0.f};
#pragma unroll
    for (int h = 0; h < H_; ++h) {
      float4 x = *(const float4*)(ea_h + (size_t)h * C_ + c);
      float4 y = *(const float4*)(ea_t + (size_t)h * C_ + c);
      a.x += x.x * y.x; a.y += x.y * y.y; a.z += x.z * y.z; a.w += x.w * y.w;
    }
    a.x /= 12.f; a.y /= 12.f; a.z /= 12.f; a.w /= 12.f;
    v[q] = a;
    local += a.x + a.y + a.z + a.w;
  }
  float s = local;
#pragma unroll
  for (int m = 32; m > 0; m >>= 1) s += __shfl_xor(s, m);
  float S = s + 1e-5f;
#pragma unroll
  for (int q = 0; q < 4; ++q) {
    int c = t * 4 + 256 * q;
    float4 o;
    o.x = v[q].x / S; o.y = v[q].y / S; o.z = v[q].z / S; o.w = v[q].w / S;
    *(float4*)&ht[(size_t)np * C_ + c] = o;
  }
}

// ---------------------------------------------------------------- D: rs GEMM (R10 form)
__global__ void k_rs(const float* __restrict__ ht, const float* __restrict__ seq,
                     float* __restrict__ rs) {
  const int pt0 = blockIdx.x * 16;     // 200 tiles
  const int n = pt0 / P_;
  const int ot = threadIdx.x & 63;
  const int jt = threadIdx.x >> 6;     // 0..3
  const int o4 = blockIdx.y * 256 + ot * 4;
  __shared__ float hlds[16 * 66];
  float4 a32[4];
  double a64[4][4];
#pragma unroll
  for (int q = 0; q < 4; ++q) {
    a32[q] = {0.f, 0.f, 0.f, 0.f};
#pragma unroll
    for (int i = 0; i < 4; ++i) a64[q][i] = 0.0;
  }
  const float* seqn = seq + (size_t)n * C_ * D_;
  for (int c0 = 0; c0 < C_; c0 += 64) {
    for (int l = threadIdx.x; l < 1024; l += 256) {
      int j = l >> 6, cc = l & 63;
      hlds[j * 66 + cc] = ht[(size_t)(pt0 + j) * C_ + c0 + cc];
    }
    __syncthreads();
#pragma unroll 4
    for (int cc = 0; cc < 64; ++cc) {
      float4 sv = *(const float4*)&seqn[(size_t)(c0 + cc) * D_ + o4];
#pragma unroll
      for (int q = 0; q < 4; ++q) {
        float w = hlds[(jt * 4 + q) * 66 + cc];
        a32[q].x += w * sv.x; a32[q].y += w * sv.y;
        a32[q].z += w * sv.z; a32[q].w += w * sv.w;
      }
    }
#pragma unroll
    for (int q = 0; q < 4; ++q) {
      a64[q][0] += (double)a32[q].x; a64[q][1] += (double)a32[q].y;
      a64[q][2] += (double)a32[q].z; a64[q][3] += (double)a32[q].w;
      a32[q] = {0.f, 0.f, 0.f, 0.f};
    }
    __syncthreads();
  }
#pragma unroll
  for (int q = 0; q < 4; ++q) {
    int p = pt0 + jt * 4 + q;
#pragma unroll
    for (int i = 0; i < 4; ++i)
      rs[(size_t)p * D_ + o4 + i] = (float)a64[q][i];
  }
}

// ---------------------------------------------------------------- E: zh & zt, MERGED (R14 form)
__global__ void k_zht(const float* __restrict__ ent_emb, const float* __restrict__ rs,
                      const int* __restrict__ hts,
                      const float* __restrict__ Wh_, const float* __restrict__ bh_,
                      const float* __restrict__ Wt_, const float* __restrict__ bt_,
                      float* __restrict__ zh_, float* __restrict__ zt_) {
  const int which = blockIdx.z;        // 0 -> zh, 1 -> zt
  const float* W    = which ? Wt_ : Wh_;
  const float* bias = which ? bt_ : bh_;
  float* out        = which ? zt_ : zh_;
  const int dbl_tanh = which ^ 1;
  const int pt0 = blockIdx.x * 16;
  const int n = pt0 / P_;
  const int ot = threadIdx.x & 63;
  const int jt = threadIdx.x >> 6;
  const int o4 = blockIdx.y * 256 + ot * 4;
  __shared__ float xlds[16 * 66];
  __shared__ int sidx[16];
  if (threadIdx.x < 16) sidx[threadIdx.x] = hts[(pt0 + threadIdx.x) * 2 + which];
  float4 a32[4];
  double a64[4][4];
#pragma unroll
  for (int q = 0; q < 4; ++q) {
    a32[q] = {0.f, 0.f, 0.f, 0.f};
#pragma unroll
    for (int i = 0; i < 4; ++i) a64[q][i] = 0.0;
  }
  __syncthreads();
  for (int k0 = 0; k0 < IN2_; k0 += 64) {
    for (int l = threadIdx.x; l < 1024; l += 256) {
      int j = l >> 6, q = l & 63;
      int kx = k0 + q;
      float val;
      if (kx < D_) val = ent_emb[(size_t)(n * E_ + sidx[j]) * D_ + kx];
      else         val = rs[(size_t)(pt0 + j) * D_ + (kx - D_)];
      xlds[j * 66 + q] = val;
    }
    __syncthreads();
#pragma unroll 4
    for (int q = 0; q < 64; ++q) {
      float4 wv = *(const float4*)&W[(size_t)(k0 + q) * EMB_ + o4];
#pragma unroll
      for (int j = 0; j < 4; ++j) {
        float x = xlds[(jt * 4 + j) * 66 + q];
        a32[j].x += x * wv.x; a32[j].y += x * wv.y;
        a32[j].z += x * wv.z; a32[j].w += x * wv.w;
      }
    }
#pragma unroll
    for (int j = 0; j < 4; ++j) {
      a64[j][0] += (double)a32[j].x; a64[j][1] += (double)a32[j].y;
      a64[j][2] += (double)a32[j].z; a64[j][3] += (double)a32[j].w;
      a32[j] = {0.f, 0.f, 0.f, 0.f};
    }
    __syncthreads();
  }
#pragma unroll
  for (int j = 0; j < 4; ++j) {
    int p = pt0 + jt * 4 + j;
#pragma unroll
    for (int i = 0; i < 4; ++i) {
      int o = o4 + i;
      double z = a64[j][i] + (double)bias[o];
      z = tanh(z);
      if (dbl_tanh) z = tanh(z);
      out[(size_t)p * EMB_ + o] = (float)z;
    }
  }
}

// ---------------------------------------------------------------- F: logits partial (all 97 r)
// Template over NCH (c-split factor). Slab = (k, bh, ch); s = (k*2+bh)*NCH+ch.
// NCH=2: Wlin = 32x97 (12.4 KB) -> 8 blk/CU (thread-capped); grid 2400 blocks
// = 9600 waves. NCH=1: exact R14/R12 kernel (proven fallback). #pragma unroll 1
// pins codegen (R11 pathology). Scalar FMA; per-output order within a slab
// (c asc within b, b asc) unchanged; slabs reduced in f64 by k_final.
// Slabs s<24 live in pA (dead-region alias), s>=24 in pB (ws tail).
template <int NCH>
__global__ __launch_bounds__(256) void k_logits_part(
    const float* __restrict__ zh, const float* __restrict__ zt,
    const float* __restrict__ Wb, float* __restrict__ pA, float* __restrict__ pB) {
  const int S   = 24 * NCH;
  const int bid = blockIdx.x;
  const int s   = bid % S;             // slab (XCD s%8 affinity: S%8==0)
  const int t   = bid / S;             // p-tile 0..49
  const int ch  = s % NCH;
  const int rest = s / NCH;
  const int k   = rest >> 1, bh = rest & 1;
  const int CW  = 64 / NCH;            // c-range width
  const int pt0 = t * 64;
  const int rt = threadIdx.x & 15;
  const int pg = threadIdx.x >> 4;     // 0..15 -> pairs pg*4+j
  const int kb0 = k * 64 + bh * 32;

  __shared__ float Wlin[(64 / NCH) * 97];

  // stage slice b: CW*97 floats = (1552/NCH) float4
  auto stage_w = [&](int b) {
    const float* src = Wb + (size_t)(kb0 + b) * 6208 + ch * CW * 97;
    const int NF4 = 1552 / NCH;
#pragma unroll
    for (int u = 0; u < NF4 / 256; ++u)
      GLOAD_LDS16(src + (u * 256 + threadIdx.x) * 4,
                  Wlin + (u * 256 + threadIdx.x) * 4);
    if (threadIdx.x < (NF4 & 255))
      GLOAD_LDS16(src + ((NF4 & ~255) + threadIdx.x) * 4,
                  Wlin + ((NF4 & ~255) + threadIdx.x) * 4);
  };

  stage_w(0);

  float acc[4][6];
  float acc6[4];
#pragma unroll
  for (int j = 0; j < 4; ++j) {
    acc6[j] = 0.f;
#pragma unroll
    for (int i = 0; i < 6; ++i) acc[j][i] = 0.f;
  }

  const float* ztb  = zt + (size_t)(pt0 + pg * 4) * EMB_ + k * 64 + ch * CW;
  const float* zh_g = zh + (size_t)(pt0 + pg * 4) * EMB_ + kb0;

  __syncthreads();                     // drains vmcnt: Wlin(b=0) ready

#pragma unroll 1
  for (int b = 0; b < 32; ++b) {
    float zhv[4];
#pragma unroll
    for (int j = 0; j < 4; ++j) zhv[j] = zh_g[(size_t)j * EMB_ + b];

#pragma unroll 1
    for (int c0 = 0; c0 < CW; c0 += 4) {
      float4 ztv[4];
#pragma unroll
      for (int j = 0; j < 4; ++j)
        ztv[j] = *(const float4*)(ztb + (size_t)j * EMB_ + c0);
      float4 pz[4];
#pragma unroll
      for (int j = 0; j < 4; ++j) {
        pz[j].x = zhv[j] * ztv[j].x; pz[j].y = zhv[j] * ztv[j].y;
        pz[j].z = zhv[j] * ztv[j].z; pz[j].w = zhv[j] * ztv[j].w;
      }
#pragma unroll
      for (int cc = 0; cc < 4; ++cc) {
        const float* wr = &Wlin[(c0 + cc) * 97];
        float w6 = wr[96];
#pragma unroll
        for (int i = 0; i < 6; ++i) {
          float w = wr[rt + 16 * i];   // compiler ds_read_b32, 16-lane broadcast
#pragma unroll
          for (int j = 0; j < 4; ++j) {
            float pzc = (cc == 0) ? pz[j].x : (cc == 1) ? pz[j].y
                      : (cc == 2) ? pz[j].z : pz[j].w;
            acc[j][i] += pzc * w;
          }
        }
#pragma unroll
        for (int j = 0; j < 4; ++j) {
          float pzc = (cc == 0) ? pz[j].x : (cc == 1) ? pz[j].y
                    : (cc == 2) ? pz[j].z : pz[j].w;
          acc6[j] += pzc * w6;
        }
      }
    }
    if (b < 31) {
      __syncthreads();                 // readers of Wlin(b) done
      stage_w(b + 1);
      __syncthreads();                 // drains vmcnt: Wlin(b+1) ready
    }
  }

  float* po = (s < 24) ? pA + (size_t)s * NP_ * NREL_
                       : pB + (size_t)(s - 24) * NP_ * NREL_;
#pragma unroll
  for (int j = 0; j < 4; ++j) {
    int p = pt0 + pg * 4 + j;
#pragma unroll
    for (int i = 0; i < 6; ++i)
      po[(size_t)p * NREL_ + rt + 16 * i] = acc[j][i];
    if (rt == 0) po[(size_t)p * NREL_ + 96] = acc6[j];
  }
}

// ---------------------------------------------------------------- G: finalize
// Sums 24 slabs from pA and nb slabs from pB (nb = 0 or 24), f64, fixed order.
__global__ void k_final(const float* __restrict__ pA, const float* __restrict__ pB,
                        int nb, const float* __restrict__ bb,
                        float* __restrict__ out) {
  const int p = blockIdx.x;
  const int r = threadIdx.x;           // 128 threads
  __shared__ double th_s;
  __shared__ int cnt[128];
  double v = 0.0;
  if (r < NREL_) {
    for (int g = 0; g < 24; ++g)
      v += (double)pA[(size_t)g * NP_ * NREL_ + (size_t)p * NREL_ + r];
    for (int g = 0; g < nb; ++g)
      v += (double)pB[(size_t)g * NP_ * NREL_ + (size_t)p * NREL_ + r];
    v += (double)bb[r];
    out[(size_t)p * NREL_ + r] = (float)v;
  }
  if (r == 0) th_s = v;
  __syncthreads();
  int pred = (r >= 1 && r < NREL_ && v > th_s) ? 1 : 0;
  cnt[r] = pred;
  __syncthreads();
  for (int s = 64; s > 0; s >>= 1) {
    if (r < s) cnt[r] += cnt[r + s];
    __syncthreads();
  }
  if (r < NREL_) {
    float pv = (r == 0) ? ((cnt[0] == 0) ? 1.f : 0.f) : (float)pred;
    out[(size_t)NP_ * NREL_ + (size_t)p * NREL_ + r] = pv;
  }
}

extern "C" void kernel_launch(void* const* d_in, const int* in_sizes, int n_in,
                              void* d_out, int out_size, void* d_ws, size_t ws_size,
                              hipStream_t stream) {
  const float* seq  = (const float*)d_in[0];
  const float* att  = (const float*)d_in[1];
  const int*   mpos = (const int*)d_in[2];
  const int*   hts  = (const int*)d_in[3];
  const float* Wh   = (const float*)d_in[4];
  const float* bh   = (const float*)d_in[5];
  const float* Wt   = (const float*)d_in[6];
  const float* bt   = (const float*)d_in[7];
  const float* Wb   = (const float*)d_in[8];
  const float* bb   = (const float*)d_in[9];
  float* out = (float*)d_out;
  float* ws = (float*)d_ws;

  float* ent_emb = ws;                   // [0, 122880)
  float* ent_att = ws + 122880;          // dead after k_ht_att
  float* ht      = ws + 2088960;         // dead after k_rs
  float* rs      = ws + 5365760;         // dead after k_zht
  float* zh      = ws + 7823360;
  float* zt      = ws + 10280960;
  // partial region A: aliases dead ent_att+ht+rs [122880, 7823360): 24 slabs
  // (24*310400 = 7,449,600 floats fits in 7,700,480).
  float* partA   = ws + 122880;
  // partial region B: ws tail [12738560, +7,449,600) -- only if ws is big enough.
  float* partB   = ws + 12738560;
  const size_t need_big = (size_t)(12738560 + 24 * NP_ * NREL_) * sizeof(float);
  const bool big = ws_size >= need_big;   // ws_size fixed -> deterministic

  k_ent_emb<<<160, 256, 0, stream>>>(seq, mpos, ent_emb);
  k_ent_att<<<7680, 256, 0, stream>>>(att, mpos, ent_att);
  k_ht_att<<<3200, 64, 0, stream>>>(ent_att, hts, ht);
  k_rs<<<dim3(200, 3), 256, 0, stream>>>(ht, seq, rs);
  k_zht<<<dim3(200, 3, 2), 256, 0, stream>>>(ent_emb, rs, hts, Wh, bh, Wt, bt, zh, zt);
  if (big) {
    k_logits_part<2><<<2400, 256, 0, stream>>>(zh, zt, Wb, partA, partB);
    k_final<<<3200, 128, 0, stream>>>(partA, partB, 24, bb, out);
  } else {
    k_logits_part<1><<<1200, 256, 0, stream>>>(zh, zt, Wb, partA, partB);
    k_final<<<3200, 128, 0, stream>>>(partA, partB, 0, bb, out);
  }
}

// Round 17
// 868.037 us; speedup vs baseline: 1.2900x; 1.2900x over previous
//
#include <hip/hip_runtime.h>
#include <hip/hip_bf16.h>
#include <math.h>

#define N_DOC 4
#define C_    1024
#define D_    768
#define H_    12
#define E_    40
#define M_    3
#define P_    800
#define NP_   3200
#define EMB_  768
#define NREL_ 97
#define IN2_  1536   // 2*D

#define GLOAD_LDS16(g, l) \
  __builtin_amdgcn_global_load_lds( \
      (const __attribute__((address_space(1))) void*)(g), \
      (__attribute__((address_space(3))) void*)(l), 16, 0, 0)

typedef __attribute__((ext_vector_type(8))) short bf16x8;
typedef __attribute__((ext_vector_type(4))) float f32x4;

// bf16 round-to-nearest-even split helpers (bit-exact, no header API dependence)
static __device__ __forceinline__ unsigned short f2bf(float x) {
  unsigned u = __builtin_bit_cast(unsigned, x);
  u = (u + 0x7FFFu + ((u >> 16) & 1u)) >> 16;
  return (unsigned short)u;
}
static __device__ __forceinline__ float bf2f(unsigned short b) {
  unsigned u = ((unsigned)b) << 16;
  return __builtin_bit_cast(float, u);
}

// ---------------------------------------------------------------- A: ent_emb
__global__ void k_ent_emb(const float* __restrict__ seq, const int* __restrict__ mpos,
                          float* __restrict__ ent_emb) {
  int ne = blockIdx.x;                 // 0..159
  int n = ne / E_, e = ne % E_;
  int base = (n * E_ + e) * M_;
  int p0 = mpos[base + 0] + 1, p1 = mpos[base + 1] + 1, p2 = mpos[base + 2] + 1;
  const float* s0 = seq + ((size_t)n * C_ + p0) * D_;
  const float* s1 = seq + ((size_t)n * C_ + p1) * D_;
  const float* s2 = seq + ((size_t)n * C_ + p2) * D_;
  float* out = ent_emb + (size_t)ne * D_;
  for (int d = threadIdx.x; d < D_; d += blockDim.x) {
    double a = s0[d], b = s1[d], c = s2[d];
    double mx = fmax(a, fmax(b, c));
    double s = exp(a - mx) + exp(b - mx) + exp(c - mx);
    out[d] = (float)(mx + log(s));
  }
}

// ---------------------------------------------------------------- B: ent_att
__global__ void k_ent_att(const float* __restrict__ att, const int* __restrict__ mpos,
                          float* __restrict__ ent_att) {
  int idx = blockIdx.x * 256 + threadIdx.x;        // exactly N*E*H*C = 1966080
  int c = idx & (C_ - 1);
  int h = (idx >> 10) % H_;
  int rem = idx / (C_ * H_);
  int e = rem % E_;
  int n = rem / E_;
  int base = (n * E_ + e) * M_;
  float acc = 0.f;
#pragma unroll
  for (int m = 0; m < M_; ++m) {
    int p = mpos[base + m] + 1;
    acc += att[(((size_t)n * H_ + h) * C_ + p) * C_ + c];
  }
  ent_att[idx] = acc / 3.0f;
}

// ---------------------------------------------------------------- C: ht_att
__global__ void k_ht_att(const float* __restrict__ ent_att, const int* __restrict__ hts,
                         float* __restrict__ ht) {
  int np = blockIdx.x;                 // 0..3199
  int n = np / P_;
  int hi = hts[np * 2 + 0], ti = hts[np * 2 + 1];
  const float* ea_h = ent_att + (size_t)(n * E_ + hi) * H_ * C_;
  const float* ea_t = ent_att + (size_t)(n * E_ + ti) * H_ * C_;
  const int t = threadIdx.x;           // 0..63
  float4 v[4];
  float local = 0.f;
#pragma unroll
  for (int q = 0; q < 4; ++q) {
    int c = t * 4 + 256 * q;
    float4 a = {0.f, 0.f, 0.f, 0.f};
#pragma unroll
    for (int h = 0; h < H_; ++h) {
      float4 x = *(const float4*)(ea_h + (size_t)h * C_ + c);
      float4 y = *(const float4*)(ea_t + (size_t)h * C_ + c);
      a.x += x.x * y.x; a.y += x.y * y.y; a.z += x.z * y.z; a.w += x.w * y.w;
    }
    a.x /= 12.f; a.y /= 12.f; a.z /= 12.f; a.w /= 12.f;
    v[q] = a;
    local += a.x + a.y + a.z + a.w;
  }
  float s = local;
#pragma unroll
  for (int m = 32; m > 0; m >>= 1) s += __shfl_xor(s, m);
  float S = s + 1e-5f;
#pragma unroll
  for (int q = 0; q < 4; ++q) {
    int c = t * 4 + 256 * q;
    float4 o;
    o.x = v[q].x / S; o.y = v[q].y / S; o.z = v[q].z / S; o.w = v[q].w / S;
    *(float4*)&ht[(size_t)np * C_ + c] = o;
  }
}

// ---------------------------------------------------------------- D: rs GEMM (R10 form)
__global__ void k_rs(const float* __restrict__ ht, const float* __restrict__ seq,
                     float* __restrict__ rs) {
  const int pt0 = blockIdx.x * 16;     // 200 tiles
  const int n = pt0 / P_;
  const int ot = threadIdx.x & 63;
  const int jt = threadIdx.x >> 6;     // 0..3
  const int o4 = blockIdx.y * 256 + ot * 4;
  __shared__ float hlds[16 * 66];
  float4 a32[4];
  double a64[4][4];
#pragma unroll
  for (int q = 0; q < 4; ++q) {
    a32[q] = {0.f, 0.f, 0.f, 0.f};
#pragma unroll
    for (int i = 0; i < 4; ++i) a64[q][i] = 0.0;
  }
  const float* seqn = seq + (size_t)n * C_ * D_;
  for (int c0 = 0; c0 < C_; c0 += 64) {
    for (int l = threadIdx.x; l < 1024; l += 256) {
      int j = l >> 6, cc = l & 63;
      hlds[j * 66 + cc] = ht[(size_t)(pt0 + j) * C_ + c0 + cc];
    }
    __syncthreads();
#pragma unroll 4
    for (int cc = 0; cc < 64; ++cc) {
      float4 sv = *(const float4*)&seqn[(size_t)(c0 + cc) * D_ + o4];
#pragma unroll
      for (int q = 0; q < 4; ++q) {
        float w = hlds[(jt * 4 + q) * 66 + cc];
        a32[q].x += w * sv.x; a32[q].y += w * sv.y;
        a32[q].z += w * sv.z; a32[q].w += w * sv.w;
      }
    }
#pragma unroll
    for (int q = 0; q < 4; ++q) {
      a64[q][0] += (double)a32[q].x; a64[q][1] += (double)a32[q].y;
      a64[q][2] += (double)a32[q].z; a64[q][3] += (double)a32[q].w;
      a32[q] = {0.f, 0.f, 0.f, 0.f};
    }
    __syncthreads();
  }
#pragma unroll
  for (int q = 0; q < 4; ++q) {
    int p = pt0 + jt * 4 + q;
#pragma unroll
    for (int i = 0; i < 4; ++i)
      rs[(size_t)p * D_ + o4 + i] = (float)a64[q][i];
  }
}

// ---------------------------------------------------------------- E: zh & zt, MERGED (R14 form)
__global__ void k_zht(const float* __restrict__ ent_emb, const float* __restrict__ rs,
                      const int* __restrict__ hts,
                      const float* __restrict__ Wh_, const float* __restrict__ bh_,
                      const float* __restrict__ Wt_, const float* __restrict__ bt_,
                      float* __restrict__ zh_, float* __restrict__ zt_) {
  const int which = blockIdx.z;        // 0 -> zh, 1 -> zt
  const float* W    = which ? Wt_ : Wh_;
  const float* bias = which ? bt_ : bh_;
  float* out        = which ? zt_ : zh_;
  const int dbl_tanh = which ^ 1;
  const int pt0 = blockIdx.x * 16;
  const int n = pt0 / P_;
  const int ot = threadIdx.x & 63;
  const int jt = threadIdx.x >> 6;
  const int o4 = blockIdx.y * 256 + ot * 4;
  __shared__ float xlds[16 * 66];
  __shared__ int sidx[16];
  if (threadIdx.x < 16) sidx[threadIdx.x] = hts[(pt0 + threadIdx.x) * 2 + which];
  float4 a32[4];
  double a64[4][4];
#pragma unroll
  for (int q = 0; q < 4; ++q) {
    a32[q] = {0.f, 0.f, 0.f, 0.f};
#pragma unroll
    for (int i = 0; i < 4; ++i) a64[q][i] = 0.0;
  }
  __syncthreads();
  for (int k0 = 0; k0 < IN2_; k0 += 64) {
    for (int l = threadIdx.x; l < 1024; l += 256) {
      int j = l >> 6, q = l & 63;
      int kx = k0 + q;
      float val;
      if (kx < D_) val = ent_emb[(size_t)(n * E_ + sidx[j]) * D_ + kx];
      else         val = rs[(size_t)(pt0 + j) * D_ + (kx - D_)];
      xlds[j * 66 + q] = val;
    }
    __syncthreads();
#pragma unroll 4
    for (int q = 0; q < 64; ++q) {
      float4 wv = *(const float4*)&W[(size_t)(k0 + q) * EMB_ + o4];
#pragma unroll
      for (int j = 0; j < 4; ++j) {
        float x = xlds[(jt * 4 + j) * 66 + q];
        a32[j].x += x * wv.x; a32[j].y += x * wv.y;
        a32[j].z += x * wv.z; a32[j].w += x * wv.w;
      }
    }
#pragma unroll
    for (int j = 0; j < 4; ++j) {
      a64[j][0] += (double)a32[j].x; a64[j][1] += (double)a32[j].y;
      a64[j][2] += (double)a32[j].z; a64[j][3] += (double)a32[j].w;
      a32[j] = {0.f, 0.f, 0.f, 0.f};
    }
    __syncthreads();
  }
#pragma unroll
  for (int j = 0; j < 4; ++j) {
    int p = pt0 + jt * 4 + j;
#pragma unroll
    for (int i = 0; i < 4; ++i) {
      int o = o4 + i;
      double z = a64[j][i] + (double)bias[o];
      z = tanh(z);
      if (dbl_tanh) z = tanh(z);
      out[(size_t)p * EMB_ + o] = (float)z;
    }
  }
}

// ---------------------------------------------------------------- W-split prep
// Packs Wb[49152][97] cols 0..95 into MFMA-B-fragment-ready bf16 hi/lo arrays.
// Frag-block (k12<12, T<128, n<6): lane l, elem e -> B[k][r]:
//   kk = (T>>1)*64 + (T&1)*32 + (l>>4)*8 + e ; row = k12*4096+kk ; r = n*16+(l&15)
// flat = (((k12*128+T)*6+n)*64+l)*8+e
__global__ void k_wsplit(const float* __restrict__ Wb,
                         unsigned short* __restrict__ Whi,
                         unsigned short* __restrict__ Wlo) {
  int g = blockIdx.x * 256 + threadIdx.x;          // 0..589823
  int l = g & 63;
  int n = (g >> 6) % 6;
  int T = (g >> 6) / 6 % 128;
  int k12 = g / 49152;
  int kk = (T >> 1) * 64 + (T & 1) * 32 + (l >> 4) * 8;
  int row0 = k12 * 4096 + kk;
  int r = n * 16 + (l & 15);
  size_t o = (size_t)g * 8;
#pragma unroll
  for (int e = 0; e < 8; ++e) {
    float v = Wb[(size_t)(row0 + e) * NREL_ + r];
    unsigned short hi = f2bf(v);
    unsigned short lo = f2bf(v - bf2f(hi));
    Whi[o + e] = hi;
    Wlo[o + e] = lo;
  }
}

// ---------------------------------------------------------------- F: logits via MFMA (r 0..95)
// 24 K-slabs (K=2048): slab s = k12*2+q. Block = 4 waves x 16 pairs = 64 pairs;
// grid 1200 (24 x 50). Per K=32 chunk: wave builds A-frag in-register
// (pz = zh*zt -> bf16 hi+lo), B-frags (6 ntiles x hi/lo) staged in LDS via
// global_load_lds, double-buffered, ONE barrier per chunk. 3-term split:
// hi*Whi + hi*Wlo + lo*Whi. Fragment layouts per m89 (16x16x32 bf16):
//   A: row=l&15, k=(l>>4)*8+e ; B: col=l&15, k=(l>>4)*8+e ;
//   D: col=lane&15, row=(lane>>4)*4+reg.
__global__ __launch_bounds__(256) void k_logits_mfma(
    const float* __restrict__ zh, const float* __restrict__ zt,
    const unsigned short* __restrict__ Whi, const unsigned short* __restrict__ Wlo,
    float* __restrict__ pA) {
  const int bid = blockIdx.x;          // 0..1199
  const int s   = bid % 24;            // slab (XCD s%8 affinity)
  const int ptb = (bid / 24) * 64;     // pair-tile base (64 pairs per block)
  const int k12 = s >> 1, q = s & 1;
  const int tid = threadIdx.x;
  const int w   = tid >> 6;            // wave 0..3
  const int l   = tid & 63;
  const int kg  = l >> 4;              // 0..3
  const int pr  = ptb + w * 16 + (l & 15);   // this lane's pair

  __shared__ __align__(16) unsigned short ldsW[2][6144];  // 2 x 12288 B

  // stage chunk tl (global chunk T = q*64+tl): 768 x 16B units, 3 rounds
  auto stage = [&](int buf, int tl) {
    int T = q * 64 + tl;
    size_t fb = (size_t)(k12 * 128 + T) * 6;
#pragma unroll
    for (int rr = 0; rr < 3; ++rr) {
      int u = rr * 256 + tid;
      int term = u / 384, rem = u % 384;
      int n = rem >> 6, lu = rem & 63;
      const unsigned short* src = (term ? Wlo : Whi) + ((fb + n) * 64 + lu) * 8;
      GLOAD_LDS16(src, &ldsW[buf][u * 8]);
    }
  };

  f32x4 acc[6];
#pragma unroll
  for (int n = 0; n < 6; ++n) acc[n] = (f32x4){0.f, 0.f, 0.f, 0.f};

  const float* ztrow = zt + (size_t)pr * EMB_ + k12 * 64;
  const float* zhrow = zh + (size_t)pr * EMB_ + k12 * 64;

  stage(0, 0);
  __syncthreads();                     // drains vmcnt: buf0 ready

  int cur = 0;
#pragma unroll 1
  for (int tl = 0; tl < 64; ++tl) {
    if (tl < 63) stage(cur ^ 1, tl + 1);   // async, overlaps compute

    int T = q * 64 + tl;
    float zhv = zhrow[T >> 1];             // b = T>>1
    int cbase = (T & 1) * 32 + kg * 8;     // this lane's 8 c-values
    float4 z0 = *(const float4*)(ztrow + cbase);
    float4 z1 = *(const float4*)(ztrow + cbase + 4);
    float zv[8] = {z0.x, z0.y, z0.z, z0.w, z1.x, z1.y, z1.z, z1.w};
    bf16x8 ahi, alo;
#pragma unroll
    for (int e = 0; e < 8; ++e) {
      float pz = zhv * zv[e];
      unsigned short h = f2bf(pz);
      unsigned short lo = f2bf(pz - bf2f(h));
      ahi[e] = (short)h;
      alo[e] = (short)lo;
    }

    const unsigned short* lp = ldsW[cur];
#pragma unroll
    for (int n = 0; n < 6; ++n) {
      bf16x8 bh = *(const bf16x8*)(lp + ((size_t)(n * 64 + l)) * 8);
      bf16x8 bl = *(const bf16x8*)(lp + ((size_t)(384 + n * 64 + l)) * 8);
      acc[n] = __builtin_amdgcn_mfma_f32_16x16x32_bf16(ahi, bh, acc[n], 0, 0, 0);
      acc[n] = __builtin_amdgcn_mfma_f32_16x16x32_bf16(ahi, bl, acc[n], 0, 0, 0);
      acc[n] = __builtin_amdgcn_mfma_f32_16x16x32_bf16(alo, bh, acc[n], 0, 0, 0);
    }
    __syncthreads();                   // readers of cur done + next slice landed
    cur ^= 1;
  }

  float* po = pA + (size_t)s * NP_ * NREL_;
  const int colr = l & 15, rowg = (l >> 4) * 4;
#pragma unroll
  for (int n = 0; n < 6; ++n)
#pragma unroll
    for (int i = 0; i < 4; ++i) {
      int p = ptb + w * 16 + rowg + i;
      po[(size_t)p * NREL_ + n * 16 + colr] = acc[n][i];
    }
}

// ---------------------------------------------------------------- F2: r=96 column (fp32, proven)
__global__ void k_r96(const float* __restrict__ zh, const float* __restrict__ zt,
                      const float* __restrict__ Wb, float* __restrict__ r96p) {
  const int pt0 = blockIdx.x * 64;
  const int k  = blockIdx.y;
  const int bh = blockIdx.z;
  const int p = pt0 + (threadIdx.x >> 1);
  const int ch = threadIdx.x & 1;
  const int kb0 = k * 64 + bh * 32;
  const float* zhr = zh + (size_t)p * EMB_ + kb0;
  const float* ztr = zt + (size_t)p * EMB_ + k * 64 + ch * 32;
  float acc = 0.f;
  for (int b = 0; b < 32; ++b) {
    float zhb = zhr[b];
    const float* w = Wb + (size_t)((kb0 + b) * 64 + ch * 32) * NREL_ + 96;
#pragma unroll 8
    for (int c = 0; c < 32; ++c)
      acc += zhb * ztr[c] * w[(size_t)c * NREL_];
  }
  acc += __shfl_xor(acc, 1);
  if (ch == 0)
    r96p[(size_t)(k * 2 + bh) * NP_ + p] = acc;
}

// ---------------------------------------------------------------- G: finalize (MFMA path)
__global__ void k_final_mfma(const float* __restrict__ pA, const float* __restrict__ r96p,
                             const float* __restrict__ bb, float* __restrict__ out) {
  const int p = blockIdx.x;
  const int r = threadIdx.x;           // 128 threads
  __shared__ double th_s;
  __shared__ int cnt[128];
  double v = 0.0;
  if (r < 96) {
    for (int g = 0; g < 24; ++g)
      v += (double)pA[(size_t)g * NP_ * NREL_ + (size_t)p * NREL_ + r];
    v += (double)bb[r];
    out[(size_t)p * NREL_ + r] = (float)v;
  } else if (r == 96) {
    for (int g = 0; g < 24; ++g)
      v += (double)r96p[(size_t)g * NP_ + p];
    v += (double)bb[96];
    out[(size_t)p * NREL_ + 96] = (float)v;
  }
  if (r == 0) th_s = v;
  __syncthreads();
  int pred = (r >= 1 && r < NREL_ && v > th_s) ? 1 : 0;
  cnt[r] = pred;
  __syncthreads();
  for (int s = 64; s > 0; s >>= 1) {
    if (r < s) cnt[r] += cnt[r + s];
    __syncthreads();
  }
  if (r < NREL_) {
    float pv = (r == 0) ? ((cnt[0] == 0) ? 1.f : 0.f) : (float)pred;
    out[(size_t)NP_ * NREL_ + (size_t)p * NREL_ + r] = pv;
  }
}

// ---------------------------------------------------------------- Fallback (R14, proven): flat logits
__global__ __launch_bounds__(256) void k_logits_flat(
    const float* __restrict__ zh, const float* __restrict__ zt,
    const float* __restrict__ Wb, float* __restrict__ part) {
  const int bid = blockIdx.x;
  const int s   = bid % 24;
  const int t   = bid / 24;
  const int k   = s >> 1, bh = s & 1;
  const int pt0 = t * 64;
  const int rt = threadIdx.x & 15;
  const int pg = threadIdx.x >> 4;
  const int kb0 = k * 64 + bh * 32;
  __shared__ float Wlin[64 * 97];
  auto stage_w = [&](int b) {
    const float* src = Wb + (size_t)(kb0 + b) * 6208;
#pragma unroll
    for (int u = 0; u < 6; ++u)
      GLOAD_LDS16(src + (u * 256 + threadIdx.x) * 4,
                  Wlin + (u * 256 + threadIdx.x) * 4);
    if (threadIdx.x < 16)
      GLOAD_LDS16(src + (1536 + threadIdx.x) * 4,
                  Wlin + (1536 + threadIdx.x) * 4);
  };
  stage_w(0);
  float acc[4][6];
  float acc6[4];
#pragma unroll
  for (int j = 0; j < 4; ++j) {
    acc6[j] = 0.f;
#pragma unroll
    for (int i = 0; i < 6; ++i) acc[j][i] = 0.f;
  }
  const float* ztb  = zt + (size_t)(pt0 + pg * 4) * EMB_ + k * 64;
  const float* zh_g = zh + (size_t)(pt0 + pg * 4) * EMB_ + kb0;
  __syncthreads();
#pragma unroll 1
  for (int b = 0; b < 32; ++b) {
    float zhv[4];
#pragma unroll
    for (int j = 0; j < 4; ++j) zhv[j] = zh_g[(size_t)j * EMB_ + b];
#pragma unroll 1
    for (int c0 = 0; c0 < 64; c0 += 4) {
      float4 ztv[4];
#pragma unroll
      for (int j = 0; j < 4; ++j)
        ztv[j] = *(const float4*)(ztb + (size_t)j * EMB_ + c0);
      float4 pz[4];
#pragma unroll
      for (int j = 0; j < 4; ++j) {
        pz[j].x = zhv[j] * ztv[j].x; pz[j].y = zhv[j] * ztv[j].y;
        pz[j].z = zhv[j] * ztv[j].z; pz[j].w = zhv[j] * ztv[j].w;
      }
#pragma unroll
      for (int cc = 0; cc < 4; ++cc) {
        const float* wr = &Wlin[(c0 + cc) * 97];
        float w6 = wr[96];
#pragma unroll
        for (int i = 0; i < 6; ++i) {
          float w = wr[rt + 16 * i];
#pragma unroll
          for (int j = 0; j < 4; ++j) {
            float pzc = (cc == 0) ? pz[j].x : (cc == 1) ? pz[j].y
                      : (cc == 2) ? pz[j].z : pz[j].w;
            acc[j][i] += pzc * w;
          }
        }
#pragma unroll
        for (int j = 0; j < 4; ++j) {
          float pzc = (cc == 0) ? pz[j].x : (cc == 1) ? pz[j].y
                    : (cc == 2) ? pz[j].z : pz[j].w;
          acc6[j] += pzc * w6;
        }
      }
    }
    if (b < 31) {
      __syncthreads();
      stage_w(b + 1);
      __syncthreads();
    }
  }
  float* po = part + (size_t)s * NP_ * NREL_;
#pragma unroll
  for (int j = 0; j < 4; ++j) {
    int p = pt0 + pg * 4 + j;
#pragma unroll
    for (int i = 0; i < 6; ++i)
      po[(size_t)p * NREL_ + rt + 16 * i] = acc[j][i];
    if (rt == 0) po[(size_t)p * NREL_ + 96] = acc6[j];
  }
}

__global__ void k_final_flat(const float* __restrict__ part, const float* __restrict__ bb,
                             float* __restrict__ out) {
  const int p = blockIdx.x;
  const int r = threadIdx.x;
  __shared__ double th_s;
  __shared__ int cnt[128];
  double v = 0.0;
  if (r < NREL_) {
    for (int g = 0; g < 24; ++g)
      v += (double)part[(size_t)g * NP_ * NREL_ + (size_t)p * NREL_ + r];
    v += (double)bb[r];
    out[(size_t)p * NREL_ + r] = (float)v;
  }
  if (r == 0) th_s = v;
  __syncthreads();
  int pred = (r >= 1 && r < NREL_ && v > th_s) ? 1 : 0;
  cnt[r] = pred;
  __syncthreads();
  for (int s = 64; s > 0; s >>= 1) {
    if (r < s) cnt[r] += cnt[r + s];
    __syncthreads();
  }
  if (r < NREL_) {
    float pv = (r == 0) ? ((cnt[0] == 0) ? 1.f : 0.f) : (float)pred;
    out[(size_t)NP_ * NREL_ + (size_t)p * NREL_ + r] = pv;
  }
}

extern "C" void kernel_launch(void* const* d_in, const int* in_sizes, int n_in,
                              void* d_out, int out_size, void* d_ws, size_t ws_size,
                              hipStream_t stream) {
  const float* seq  = (const float*)d_in[0];
  const float* att  = (const float*)d_in[1];
  const int*   mpos = (const int*)d_in[2];
  const int*   hts  = (const int*)d_in[3];
  const float* Wh   = (const float*)d_in[4];
  const float* bh   = (const float*)d_in[5];
  const float* Wt   = (const float*)d_in[6];
  const float* bt   = (const float*)d_in[7];
  const float* Wb   = (const float*)d_in[8];
  const float* bb   = (const float*)d_in[9];
  float* out = (float*)d_out;
  float* ws = (float*)d_ws;

  float* ent_emb = ws;                   // [0, 122880)
  float* ent_att = ws + 122880;          // dead after k_ht_att
  float* ht      = ws + 2088960;         // dead after k_rs
  float* rs      = ws + 5365760;         // dead after k_zht
  float* zh      = ws + 7823360;
  float* zt      = ws + 10280960;        // ends 12738560
  // MFMA path layout (all float-offsets; NO overlaps):
  //   pA   [122880, 7572480)        24 slabs x 310400 (dead-region alias)
  //   r96p [12738560, 12815360)     24 x 3200
  //   Whi  [12815360, 15174656)     4,718,592 bf16 = 2,359,296 float-equiv
  //   Wlo  [15174656, 17533952)     4,718,592 bf16 = 2,359,296 float-equiv
  float* pA   = ws + 122880;
  float* r96p = ws + 12738560;
  unsigned short* Whi = (unsigned short*)(ws + 12815360);
  unsigned short* Wlo = (unsigned short*)(ws + 15174656);
  const bool big = ws_size >= (size_t)17533952 * sizeof(float);  // 70.1 MB

  if (big) k_wsplit<<<2304, 256, 0, stream>>>(Wb, Whi, Wlo);
  k_ent_emb<<<160, 256, 0, stream>>>(seq, mpos, ent_emb);
  k_ent_att<<<7680, 256, 0, stream>>>(att, mpos, ent_att);
  k_ht_att<<<3200, 64, 0, stream>>>(ent_att, hts, ht);
  k_rs<<<dim3(200, 3), 256, 0, stream>>>(ht, seq, rs);
  k_zht<<<dim3(200, 3, 2), 256, 0, stream>>>(ent_emb, rs, hts, Wh, bh, Wt, bt, zh, zt);
  if (big) {
    k_r96<<<dim3(50, 12, 2), 128, 0, stream>>>(zh, zt, Wb, r96p);
    k_logits_mfma<<<1200, 256, 0, stream>>>(zh, zt, Whi, Wlo, pA);
    k_final_mfma<<<3200, 128, 0, stream>>>(pA, r96p, bb, out);
  } else {
    k_logits_flat<<<1200, 256, 0, stream>>>(zh, zt, Wb, pA);
    k_final_flat<<<3200, 128, 0, stream>>>(pA, bb, out);
  }
}

// Round 18
// 601.986 us; speedup vs baseline: 1.8601x; 1.4420x over previous
//
#include <hip/hip_runtime.h>
#include <hip/hip_bf16.h>
#include <math.h>

#define N_DOC 4
#define C_    1024
#define D_    768
#define H_    12
#define E_    40
#define M_    3
#define P_    800
#define NP_   3200
#define EMB_  768
#define NREL_ 97
#define IN2_  1536   // 2*D

#define GLOAD_LDS16(g, l) \
  __builtin_amdgcn_global_load_lds( \
      (const __attribute__((address_space(1))) void*)(g), \
      (__attribute__((address_space(3))) void*)(l), 16, 0, 0)

typedef __attribute__((ext_vector_type(8))) short bf16x8;
typedef __attribute__((ext_vector_type(4))) float f32x4;

static __device__ __forceinline__ unsigned short f2bf(float x) {
  unsigned u = __builtin_bit_cast(unsigned, x);
  u = (u + 0x7FFFu + ((u >> 16) & 1u)) >> 16;
  return (unsigned short)u;
}
static __device__ __forceinline__ float bf2f(unsigned short b) {
  unsigned u = ((unsigned)b) << 16;
  return __builtin_bit_cast(float, u);
}

// ---------------------------------------------------------------- A: ent_emb
__global__ void k_ent_emb(const float* __restrict__ seq, const int* __restrict__ mpos,
                          float* __restrict__ ent_emb) {
  int ne = blockIdx.x;                 // 0..159
  int n = ne / E_, e = ne % E_;
  int base = (n * E_ + e) * M_;
  int p0 = mpos[base + 0] + 1, p1 = mpos[base + 1] + 1, p2 = mpos[base + 2] + 1;
  const float* s0 = seq + ((size_t)n * C_ + p0) * D_;
  const float* s1 = seq + ((size_t)n * C_ + p1) * D_;
  const float* s2 = seq + ((size_t)n * C_ + p2) * D_;
  float* out = ent_emb + (size_t)ne * D_;
  for (int d = threadIdx.x; d < D_; d += blockDim.x) {
    double a = s0[d], b = s1[d], c = s2[d];
    double mx = fmax(a, fmax(b, c));
    double s = exp(a - mx) + exp(b - mx) + exp(c - mx);
    out[d] = (float)(mx + log(s));
  }
}

// ---------------------------------------------------------------- B: ent_att
__global__ void k_ent_att(const float* __restrict__ att, const int* __restrict__ mpos,
                          float* __restrict__ ent_att) {
  int idx = blockIdx.x * 256 + threadIdx.x;        // exactly N*E*H*C = 1966080
  int c = idx & (C_ - 1);
  int h = (idx >> 10) % H_;
  int rem = idx / (C_ * H_);
  int e = rem % E_;
  int n = rem / E_;
  int base = (n * E_ + e) * M_;
  float acc = 0.f;
#pragma unroll
  for (int m = 0; m < M_; ++m) {
    int p = mpos[base + m] + 1;
    acc += att[(((size_t)n * H_ + h) * C_ + p) * C_ + c];
  }
  ent_att[idx] = acc / 3.0f;
}

// ---------------------------------------------------------------- C: ht_att
__global__ void k_ht_att(const float* __restrict__ ent_att, const int* __restrict__ hts,
                         float* __restrict__ ht) {
  int np = blockIdx.x;                 // 0..3199
  int n = np / P_;
  int hi = hts[np * 2 + 0], ti = hts[np * 2 + 1];
  const float* ea_h = ent_att + (size_t)(n * E_ + hi) * H_ * C_;
  const float* ea_t = ent_att + (size_t)(n * E_ + ti) * H_ * C_;
  const int t = threadIdx.x;           // 0..63
  float4 v[4];
  float local = 0.f;
#pragma unroll
  for (int q = 0; q < 4; ++q) {
    int c = t * 4 + 256 * q;
    float4 a = {0.f, 0.f, 0.f, 0.f};
#pragma unroll
    for (int h = 0; h < H_; ++h) {
      float4 x = *(const float4*)(ea_h + (size_t)h * C_ + c);
      float4 y = *(const float4*)(ea_t + (size_t)h * C_ + c);
      a.x += x.x * y.x; a.y += x.y * y.y; a.z += x.z * y.z; a.w += x.w * y.w;
    }
    a.x /= 12.f; a.y /= 12.f; a.z /= 12.f; a.w /= 12.f;
    v[q] = a;
    local += a.x + a.y + a.z + a.w;
  }
  float s = local;
#pragma unroll
  for (int m = 32; m > 0; m >>= 1) s += __shfl_xor(s, m);
  float S = s + 1e-5f;
#pragma unroll
  for (int q = 0; q < 4; ++q) {
    int c = t * 4 + 256 * q;
    float4 o;
    o.x = v[q].x / S; o.y = v[q].y / S; o.z = v[q].z / S; o.w = v[q].w / S;
    *(float4*)&ht[(size_t)np * C_ + c] = o;
  }
}

// ---------------------------------------------------------------- D: rs GEMM (R10 form)
__global__ void k_rs(const float* __restrict__ ht, const float* __restrict__ seq,
                     float* __restrict__ rs) {
  const int pt0 = blockIdx.x * 16;     // 200 tiles
  const int n = pt0 / P_;
  const int ot = threadIdx.x & 63;
  const int jt = threadIdx.x >> 6;     // 0..3
  const int o4 = blockIdx.y * 256 + ot * 4;
  __shared__ float hlds[16 * 66];
  float4 a32[4];
  double a64[4][4];
#pragma unroll
  for (int q = 0; q < 4; ++q) {
    a32[q] = {0.f, 0.f, 0.f, 0.f};
#pragma unroll
    for (int i = 0; i < 4; ++i) a64[q][i] = 0.0;
  }
  const float* seqn = seq + (size_t)n * C_ * D_;
  for (int c0 = 0; c0 < C_; c0 += 64) {
    for (int l = threadIdx.x; l < 1024; l += 256) {
      int j = l >> 6, cc = l & 63;
      hlds[j * 66 + cc] = ht[(size_t)(pt0 + j) * C_ + c0 + cc];
    }
    __syncthreads();
#pragma unroll 4
    for (int cc = 0; cc < 64; ++cc) {
      float4 sv = *(const float4*)&seqn[(size_t)(c0 + cc) * D_ + o4];
#pragma unroll
      for (int q = 0; q < 4; ++q) {
        float w = hlds[(jt * 4 + q) * 66 + cc];
        a32[q].x += w * sv.x; a32[q].y += w * sv.y;
        a32[q].z += w * sv.z; a32[q].w += w * sv.w;
      }
    }
#pragma unroll
    for (int q = 0; q < 4; ++q) {
      a64[q][0] += (double)a32[q].x; a64[q][1] += (double)a32[q].y;
      a64[q][2] += (double)a32[q].z; a64[q][3] += (double)a32[q].w;
      a32[q] = {0.f, 0.f, 0.f, 0.f};
    }
    __syncthreads();
  }
#pragma unroll
  for (int q = 0; q < 4; ++q) {
    int p = pt0 + jt * 4 + q;
#pragma unroll
    for (int i = 0; i < 4; ++i)
      rs[(size_t)p * D_ + o4 + i] = (float)a64[q][i];
  }
}

// ---------------------------------------------------------------- E (fallback): zh & zt merged
__global__ void k_zht(const float* __restrict__ ent_emb, const float* __restrict__ rs,
                      const int* __restrict__ hts,
                      const float* __restrict__ Wh_, const float* __restrict__ bh_,
                      const float* __restrict__ Wt_, const float* __restrict__ bt_,
                      float* __restrict__ zh_, float* __restrict__ zt_) {
  const int which = blockIdx.z;        // 0 -> zh, 1 -> zt
  const float* W    = which ? Wt_ : Wh_;
  const float* bias = which ? bt_ : bh_;
  float* out        = which ? zt_ : zh_;
  const int dbl_tanh = which ^ 1;
  const int pt0 = blockIdx.x * 16;
  const int n = pt0 / P_;
  const int ot = threadIdx.x & 63;
  const int jt = threadIdx.x >> 6;
  const int o4 = blockIdx.y * 256 + ot * 4;
  __shared__ float xlds[16 * 66];
  __shared__ int sidx[16];
  if (threadIdx.x < 16) sidx[threadIdx.x] = hts[(pt0 + threadIdx.x) * 2 + which];
  float4 a32[4];
  double a64[4][4];
#pragma unroll
  for (int q = 0; q < 4; ++q) {
    a32[q] = {0.f, 0.f, 0.f, 0.f};
#pragma unroll
    for (int i = 0; i < 4; ++i) a64[q][i] = 0.0;
  }
  __syncthreads();
  for (int k0 = 0; k0 < IN2_; k0 += 64) {
    for (int l = threadIdx.x; l < 1024; l += 256) {
      int j = l >> 6, q = l & 63;
      int kx = k0 + q;
      float val;
      if (kx < D_) val = ent_emb[(size_t)(n * E_ + sidx[j]) * D_ + kx];
      else         val = rs[(size_t)(pt0 + j) * D_ + (kx - D_)];
      xlds[j * 66 + q] = val;
    }
    __syncthreads();
#pragma unroll 4
    for (int q = 0; q < 64; ++q) {
      float4 wv = *(const float4*)&W[(size_t)(k0 + q) * EMB_ + o4];
#pragma unroll
      for (int j = 0; j < 4; ++j) {
        float x = xlds[(jt * 4 + j) * 66 + q];
        a32[j].x += x * wv.x; a32[j].y += x * wv.y;
        a32[j].z += x * wv.z; a32[j].w += x * wv.w;
      }
    }
#pragma unroll
    for (int j = 0; j < 4; ++j) {
      a64[j][0] += (double)a32[j].x; a64[j][1] += (double)a32[j].y;
      a64[j][2] += (double)a32[j].z; a64[j][3] += (double)a32[j].w;
      a32[j] = {0.f, 0.f, 0.f, 0.f};
    }
    __syncthreads();
  }
#pragma unroll
  for (int j = 0; j < 4; ++j) {
    int p = pt0 + jt * 4 + j;
#pragma unroll
    for (int i = 0; i < 4; ++i) {
      int o = o4 + i;
      double z = a64[j][i] + (double)bias[o];
      z = tanh(z);
      if (dbl_tanh) z = tanh(z);
      out[(size_t)p * EMB_ + o] = (float)z;
    }
  }
}

// ---------------------------------------------------------------- W-split prep (logits Wb)
__global__ void k_wsplit(const float* __restrict__ Wb,
                         unsigned short* __restrict__ Whi,
                         unsigned short* __restrict__ Wlo) {
  int g = blockIdx.x * 256 + threadIdx.x;          // 0..589823
  int l = g & 63;
  int n = (g >> 6) % 6;
  int T = (g >> 6) / 6 % 128;
  int k12 = g / 49152;
  int kk = (T >> 1) * 64 + (T & 1) * 32 + (l >> 4) * 8;
  int row0 = k12 * 4096 + kk;
  int r = n * 16 + (l & 15);
  size_t o = (size_t)g * 8;
#pragma unroll
  for (int e = 0; e < 8; ++e) {
    float v = Wb[(size_t)(row0 + e) * NREL_ + r];
    unsigned short hi = f2bf(v);
    unsigned short lo = f2bf(v - bf2f(hi));
    Whi[o + e] = hi;
    Wlo[o + e] = lo;
  }
}

// ---------------------------------------------------------------- W-split prep (zht Wh/Wt)
// Packs W[1536][768] into fragment layout: chunk T<48 (k=32), ntile n<48 (o=16):
//   lane l, elem e -> k = T*32+(l>>4)*8+e, o = n*16+(l&15)
//   flat = ((T*48+n)*64+l)*8+e ; variant stride 1,179,648 shorts.
__global__ void k_wsplit_zht(const float* __restrict__ Wh_, const float* __restrict__ Wt_,
                             unsigned short* __restrict__ Zhi,
                             unsigned short* __restrict__ Zlo) {
  int g = blockIdx.x * 256 + threadIdx.x;          // 0..294911
  int which = g / 147456;
  int rem = g % 147456;
  int l = rem & 63;
  int n = (rem >> 6) % 48;
  int T = (rem >> 6) / 48;
  const float* W = which ? Wt_ : Wh_;
  int k0 = T * 32 + (l >> 4) * 8;
  int o = n * 16 + (l & 15);
  size_t off = ((size_t)which * 147456 + (size_t)(T * 48 + n) * 64 + l) * 8;
#pragma unroll
  for (int e = 0; e < 8; ++e) {
    float v = W[(size_t)(k0 + e) * EMB_ + o];
    unsigned short hi = f2bf(v);
    unsigned short lo = f2bf(v - bf2f(hi));
    Zhi[off + e] = hi;
    Zlo[off + e] = lo;
  }
}

// ---------------------------------------------------------------- E': zh & zt via MFMA
// Grid (50 ptile, 8 otile, 2 which). Block = 4 waves x 16 pairs = 64 pairs x 96 o.
// K-loop: 48 chunks of 32. Chunks 0..23 read gathered ent_emb rows; 24..47 read
// rs rows (boundary aligns). A built in-register (hi/lo bf16); B staged in LDS
// (6 ntiles x hi/lo) via global_load_lds, dbuf, 1 barrier/chunk. 3-term split.
// Epilogue: + bias, f64 tanh (x2 for zh).
__global__ __launch_bounds__(256) void k_zht_mfma(
    const float* __restrict__ ent_emb, const float* __restrict__ rs,
    const int* __restrict__ hts,
    const unsigned short* __restrict__ Zhi, const unsigned short* __restrict__ Zlo,
    const float* __restrict__ bh_, const float* __restrict__ bt_,
    float* __restrict__ zh_, float* __restrict__ zt_) {
  const int which = blockIdx.z;
  const float* bias = which ? bt_ : bh_;
  float* out = which ? zt_ : zh_;
  const int ptb = blockIdx.x * 64;
  const int n0  = blockIdx.y * 6;      // ntile base (o base = n0*16)
  const int tid = threadIdx.x;
  const int w   = tid >> 6;
  const int l   = tid & 63;
  const int kg  = l >> 4;
  const int pr  = ptb + w * 16 + (l & 15);
  const int doc = pr / P_;
  const int idx = hts[pr * 2 + which];
  const float* eb = ent_emb + (size_t)(doc * E_ + idx) * D_;
  const float* rb = rs + (size_t)pr * D_;

  __shared__ __align__(16) unsigned short ldsW[2][6144];  // 2 x 12288 B

  const unsigned short* Zh = Zhi + (size_t)which * 147456 * 8;
  const unsigned short* Zl = Zlo + (size_t)which * 147456 * 8;

  auto stage = [&](int buf, int T) {
#pragma unroll
    for (int rr = 0; rr < 3; ++rr) {
      int u = rr * 256 + tid;
      int term = u / 384, rem = u % 384;
      int nn = rem >> 6, lu = rem & 63;
      const unsigned short* src = (term ? Zl : Zh) +
          ((size_t)(T * 48 + n0 + nn) * 64 + lu) * 8;
      GLOAD_LDS16(src, &ldsW[buf][u * 8]);
    }
  };

  f32x4 acc[6];
#pragma unroll
  for (int nn = 0; nn < 6; ++nn) acc[nn] = (f32x4){0.f, 0.f, 0.f, 0.f};

  stage(0, 0);
  __syncthreads();

  int cur = 0;
#pragma unroll 1
  for (int T = 0; T < 48; ++T) {
    if (T < 47) stage(cur ^ 1, T + 1);

    int kx = T * 32 + kg * 8;
    const float* src = (T < 24) ? (eb + kx) : (rb + kx - D_);
    float4 z0 = *(const float4*)(src);
    float4 z1 = *(const float4*)(src + 4);
    float zv[8] = {z0.x, z0.y, z0.z, z0.w, z1.x, z1.y, z1.z, z1.w};
    bf16x8 ahi, alo;
#pragma unroll
    for (int e = 0; e < 8; ++e) {
      unsigned short h = f2bf(zv[e]);
      unsigned short lo = f2bf(zv[e] - bf2f(h));
      ahi[e] = (short)h;
      alo[e] = (short)lo;
    }

    const unsigned short* lp = ldsW[cur];
#pragma unroll
    for (int nn = 0; nn < 6; ++nn) {
      bf16x8 bh = *(const bf16x8*)(lp + ((size_t)(nn * 64 + l)) * 8);
      bf16x8 bl = *(const bf16x8*)(lp + ((size_t)(384 + nn * 64 + l)) * 8);
      acc[nn] = __builtin_amdgcn_mfma_f32_16x16x32_bf16(ahi, bh, acc[nn], 0, 0, 0);
      acc[nn] = __builtin_amdgcn_mfma_f32_16x16x32_bf16(ahi, bl, acc[nn], 0, 0, 0);
      acc[nn] = __builtin_amdgcn_mfma_f32_16x16x32_bf16(alo, bh, acc[nn], 0, 0, 0);
    }
    __syncthreads();
    cur ^= 1;
  }

  const int colr = l & 15, rowg = (l >> 4) * 4;
#pragma unroll
  for (int nn = 0; nn < 6; ++nn)
#pragma unroll
    for (int i = 0; i < 4; ++i) {
      int p = ptb + w * 16 + rowg + i;
      int o = (n0 + nn) * 16 + colr;
      double z = (double)acc[nn][i] + (double)bias[o];
      z = tanh(z);
      if (which == 0) z = tanh(z);
      out[(size_t)p * EMB_ + o] = (float)z;
    }
}

// ---------------------------------------------------------------- F: logits via MFMA (r 0..95)
__global__ __launch_bounds__(256) void k_logits_mfma(
    const float* __restrict__ zh, const float* __restrict__ zt,
    const unsigned short* __restrict__ Whi, const unsigned short* __restrict__ Wlo,
    float* __restrict__ pA) {
  const int bid = blockIdx.x;          // 0..1199
  const int s   = bid % 24;            // slab (XCD s%8 affinity)
  const int ptb = (bid / 24) * 64;     // pair-tile base
  const int k12 = s >> 1, q = s & 1;
  const int tid = threadIdx.x;
  const int w   = tid >> 6;
  const int l   = tid & 63;
  const int kg  = l >> 4;
  const int pr  = ptb + w * 16 + (l & 15);

  __shared__ __align__(16) unsigned short ldsW[2][6144];

  auto stage = [&](int buf, int tl) {
    int T = q * 64 + tl;
    size_t fb = (size_t)(k12 * 128 + T) * 6;
#pragma unroll
    for (int rr = 0; rr < 3; ++rr) {
      int u = rr * 256 + tid;
      int term = u / 384, rem = u % 384;
      int n = rem >> 6, lu = rem & 63;
      const unsigned short* src = (term ? Wlo : Whi) + ((fb + n) * 64 + lu) * 8;
      GLOAD_LDS16(src, &ldsW[buf][u * 8]);
    }
  };

  f32x4 acc[6];
#pragma unroll
  for (int n = 0; n < 6; ++n) acc[n] = (f32x4){0.f, 0.f, 0.f, 0.f};

  const float* ztrow = zt + (size_t)pr * EMB_ + k12 * 64;
  const float* zhrow = zh + (size_t)pr * EMB_ + k12 * 64;

  stage(0, 0);
  __syncthreads();

  int cur = 0;
#pragma unroll 1
  for (int tl = 0; tl < 64; ++tl) {
    if (tl < 63) stage(cur ^ 1, tl + 1);

    int T = q * 64 + tl;
    float zhv = zhrow[T >> 1];
    int cbase = (T & 1) * 32 + kg * 8;
    float4 z0 = *(const float4*)(ztrow + cbase);
    float4 z1 = *(const float4*)(ztrow + cbase + 4);
    float zv[8] = {z0.x, z0.y, z0.z, z0.w, z1.x, z1.y, z1.z, z1.w};
    bf16x8 ahi, alo;
#pragma unroll
    for (int e = 0; e < 8; ++e) {
      float pz = zhv * zv[e];
      unsigned short h = f2bf(pz);
      unsigned short lo = f2bf(pz - bf2f(h));
      ahi[e] = (short)h;
      alo[e] = (short)lo;
    }

    const unsigned short* lp = ldsW[cur];
#pragma unroll
    for (int n = 0; n < 6; ++n) {
      bf16x8 bh = *(const bf16x8*)(lp + ((size_t)(n * 64 + l)) * 8);
      bf16x8 bl = *(const bf16x8*)(lp + ((size_t)(384 + n * 64 + l)) * 8);
      acc[n] = __builtin_amdgcn_mfma_f32_16x16x32_bf16(ahi, bh, acc[n], 0, 0, 0);
      acc[n] = __builtin_amdgcn_mfma_f32_16x16x32_bf16(ahi, bl, acc[n], 0, 0, 0);
      acc[n] = __builtin_amdgcn_mfma_f32_16x16x32_bf16(alo, bh, acc[n], 0, 0, 0);
    }
    __syncthreads();
    cur ^= 1;
  }

  float* po = pA + (size_t)s * NP_ * NREL_;
  const int colr = l & 15, rowg = (l >> 4) * 4;
#pragma unroll
  for (int n = 0; n < 6; ++n)
#pragma unroll
    for (int i = 0; i < 4; ++i) {
      int p = ptb + w * 16 + rowg + i;
      po[(size_t)p * NREL_ + n * 16 + colr] = acc[n][i];
    }
}

// ---------------------------------------------------------------- F2: r=96 column (fp32)
__global__ void k_r96(const float* __restrict__ zh, const float* __restrict__ zt,
                      const float* __restrict__ Wb, float* __restrict__ r96p) {
  const int pt0 = blockIdx.x * 64;
  const int k  = blockIdx.y;
  const int bh = blockIdx.z;
  const int p = pt0 + (threadIdx.x >> 1);
  const int ch = threadIdx.x & 1;
  const int kb0 = k * 64 + bh * 32;
  const float* zhr = zh + (size_t)p * EMB_ + kb0;
  const float* ztr = zt + (size_t)p * EMB_ + k * 64 + ch * 32;
  float acc = 0.f;
  for (int b = 0; b < 32; ++b) {
    float zhb = zhr[b];
    const float* w = Wb + (size_t)((kb0 + b) * 64 + ch * 32) * NREL_ + 96;
#pragma unroll 8
    for (int c = 0; c < 32; ++c)
      acc += zhb * ztr[c] * w[(size_t)c * NREL_];
  }
  acc += __shfl_xor(acc, 1);
  if (ch == 0)
    r96p[(size_t)(k * 2 + bh) * NP_ + p] = acc;
}

// ---------------------------------------------------------------- G: finalize (MFMA path)
__global__ void k_final_mfma(const float* __restrict__ pA, const float* __restrict__ r96p,
                             const float* __restrict__ bb, float* __restrict__ out) {
  const int p = blockIdx.x;
  const int r = threadIdx.x;           // 128 threads
  __shared__ double th_s;
  __shared__ int cnt[128];
  double v = 0.0;
  if (r < 96) {
    for (int g = 0; g < 24; ++g)
      v += (double)pA[(size_t)g * NP_ * NREL_ + (size_t)p * NREL_ + r];
    v += (double)bb[r];
    out[(size_t)p * NREL_ + r] = (float)v;
  } else if (r == 96) {
    for (int g = 0; g < 24; ++g)
      v += (double)r96p[(size_t)g * NP_ + p];
    v += (double)bb[96];
    out[(size_t)p * NREL_ + 96] = (float)v;
  }
  if (r == 0) th_s = v;
  __syncthreads();
  int pred = (r >= 1 && r < NREL_ && v > th_s) ? 1 : 0;
  cnt[r] = pred;
  __syncthreads();
  for (int s = 64; s > 0; s >>= 1) {
    if (r < s) cnt[r] += cnt[r + s];
    __syncthreads();
  }
  if (r < NREL_) {
    float pv = (r == 0) ? ((cnt[0] == 0) ? 1.f : 0.f) : (float)pred;
    out[(size_t)NP_ * NREL_ + (size_t)p * NREL_ + r] = pv;
  }
}

// ---------------------------------------------------------------- Fallback flat logits + final
__global__ __launch_bounds__(256) void k_logits_flat(
    const float* __restrict__ zh, const float* __restrict__ zt,
    const float* __restrict__ Wb, float* __restrict__ part) {
  const int bid = blockIdx.x;
  const int s   = bid % 24;
  const int t   = bid / 24;
  const int k   = s >> 1, bh = s & 1;
  const int pt0 = t * 64;
  const int rt = threadIdx.x & 15;
  const int pg = threadIdx.x >> 4;
  const int kb0 = k * 64 + bh * 32;
  __shared__ float Wlin[64 * 97];
  auto stage_w = [&](int b) {
    const float* src = Wb + (size_t)(kb0 + b) * 6208;
#pragma unroll
    for (int u = 0; u < 6; ++u)
      GLOAD_LDS16(src + (u * 256 + threadIdx.x) * 4,
                  Wlin + (u * 256 + threadIdx.x) * 4);
    if (threadIdx.x < 16)
      GLOAD_LDS16(src + (1536 + threadIdx.x) * 4,
                  Wlin + (1536 + threadIdx.x) * 4);
  };
  stage_w(0);
  float acc[4][6];
  float acc6[4];
#pragma unroll
  for (int j = 0; j < 4; ++j) {
    acc6[j] = 0.f;
#pragma unroll
    for (int i = 0; i < 6; ++i) acc[j][i] = 0.f;
  }
  const float* ztb  = zt + (size_t)(pt0 + pg * 4) * EMB_ + k * 64;
  const float* zh_g = zh + (size_t)(pt0 + pg * 4) * EMB_ + kb0;
  __syncthreads();
#pragma unroll 1
  for (int b = 0; b < 32; ++b) {
    float zhv[4];
#pragma unroll
    for (int j = 0; j < 4; ++j) zhv[j] = zh_g[(size_t)j * EMB_ + b];
#pragma unroll 1
    for (int c0 = 0; c0 < 64; c0 += 4) {
      float4 ztv[4];
#pragma unroll
      for (int j = 0; j < 4; ++j)
        ztv[j] = *(const float4*)(ztb + (size_t)j * EMB_ + c0);
      float4 pz[4];
#pragma unroll
      for (int j = 0; j < 4; ++j) {
        pz[j].x = zhv[j] * ztv[j].x; pz[j].y = zhv[j] * ztv[j].y;
        pz[j].z = zhv[j] * ztv[j].z; pz[j].w = zhv[j] * ztv[j].w;
      }
#pragma unroll
      for (int cc = 0; cc < 4; ++cc) {
        const float* wr = &Wlin[(c0 + cc) * 97];
        float w6 = wr[96];
#pragma unroll
        for (int i = 0; i < 6; ++i) {
          float w = wr[rt + 16 * i];
#pragma unroll
          for (int j = 0; j < 4; ++j) {
            float pzc = (cc == 0) ? pz[j].x : (cc == 1) ? pz[j].y
                      : (cc == 2) ? pz[j].z : pz[j].w;
            acc[j][i] += pzc * w;
          }
        }
#pragma unroll
        for (int j = 0; j < 4; ++j) {
          float pzc = (cc == 0) ? pz[j].x : (cc == 1) ? pz[j].y
                    : (cc == 2) ? pz[j].z : pz[j].w;
          acc6[j] += pzc * w6;
        }
      }
    }
    if (b < 31) {
      __syncthreads();
      stage_w(b + 1);
      __syncthreads();
    }
  }
  float* po = part + (size_t)s * NP_ * NREL_;
#pragma unroll
  for (int j = 0; j < 4; ++j) {
    int p = pt0 + pg * 4 + j;
#pragma unroll
    for (int i = 0; i < 6; ++i)
      po[(size_t)p * NREL_ + rt + 16 * i] = acc[j][i];
    if (rt == 0) po[(size_t)p * NREL_ + 96] = acc6[j];
  }
}

__global__ void k_final_flat(const float* __restrict__ part, const float* __restrict__ bb,
                             float* __restrict__ out) {
  const int p = blockIdx.x;
  const int r = threadIdx.x;
  __shared__ double th_s;
  __shared__ int cnt[128];
  double v = 0.0;
  if (r < NREL_) {
    for (int g = 0; g < 24; ++g)
      v += (double)part[(size_t)g * NP_ * NREL_ + (size_t)p * NREL_ + r];
    v += (double)bb[r];
    out[(size_t)p * NREL_ + r] = (float)v;
  }
  if (r == 0) th_s = v;
  __syncthreads();
  int pred = (r >= 1 && r < NREL_ && v > th_s) ? 1 : 0;
  cnt[r] = pred;
  __syncthreads();
  for (int s = 64; s > 0; s >>= 1) {
    if (r < s) cnt[r] += cnt[r + s];
    __syncthreads();
  }
  if (r < NREL_) {
    float pv = (r == 0) ? ((cnt[0] == 0) ? 1.f : 0.f) : (float)pred;
    out[(size_t)NP_ * NREL_ + (size_t)p * NREL_ + r] = pv;
  }
}

extern "C" void kernel_launch(void* const* d_in, const int* in_sizes, int n_in,
                              void* d_out, int out_size, void* d_ws, size_t ws_size,
                              hipStream_t stream) {
  const float* seq  = (const float*)d_in[0];
  const float* att  = (const float*)d_in[1];
  const int*   mpos = (const int*)d_in[2];
  const int*   hts  = (const int*)d_in[3];
  const float* Wh   = (const float*)d_in[4];
  const float* bh   = (const float*)d_in[5];
  const float* Wt   = (const float*)d_in[6];
  const float* bt   = (const float*)d_in[7];
  const float* Wb   = (const float*)d_in[8];
  const float* bb   = (const float*)d_in[9];
  float* out = (float*)d_out;
  float* ws = (float*)d_ws;

  float* ent_emb = ws;                   // [0, 122880)
  float* ent_att = ws + 122880;          // dead after k_ht_att
  float* ht      = ws + 2088960;         // dead after k_rs
  float* rs      = ws + 5365760;         // dead after zht
  float* zh      = ws + 7823360;
  float* zt      = ws + 10280960;        // ends 12738560
  // MFMA path layout (float-offsets; no overlaps):
  //   pA    [122880, 7572480)      24 slabs x 310400 (dead-region alias)
  //   r96p  [12738560, 12815360)   24 x 3200
  //   Whi   [12815360, 15174656)   4,718,592 bf16
  //   Wlo   [15174656, 17533952)   4,718,592 bf16
  //   Zhi   [17533952, 18713600)   2 x 1,179,648 bf16 (Wh,Wt hi)
  //   Zlo   [18713600, 19893248)   2 x 1,179,648 bf16 (Wh,Wt lo)
  float* pA   = ws + 122880;
  float* r96p = ws + 12738560;
  unsigned short* Whi = (unsigned short*)(ws + 12815360);
  unsigned short* Wlo = (unsigned short*)(ws + 15174656);
  unsigned short* Zhi = (unsigned short*)(ws + 17533952);
  unsigned short* Zlo = (unsigned short*)(ws + 18713600);
  const bool big = ws_size >= (size_t)19893248 * sizeof(float);  // 79.6 MB

  if (big) {
    k_wsplit<<<2304, 256, 0, stream>>>(Wb, Whi, Wlo);
    k_wsplit_zht<<<1152, 256, 0, stream>>>(Wh, Wt, Zhi, Zlo);
  }
  k_ent_emb<<<160, 256, 0, stream>>>(seq, mpos, ent_emb);
  k_ent_att<<<7680, 256, 0, stream>>>(att, mpos, ent_att);
  k_ht_att<<<3200, 64, 0, stream>>>(ent_att, hts, ht);
  k_rs<<<dim3(200, 3), 256, 0, stream>>>(ht, seq, rs);
  if (big) {
    k_zht_mfma<<<dim3(50, 8, 2), 256, 0, stream>>>(ent_emb, rs, hts, Zhi, Zlo,
                                                   bh, bt, zh, zt);
    k_r96<<<dim3(50, 12, 2), 128, 0, stream>>>(zh, zt, Wb, r96p);
    k_logits_mfma<<<1200, 256, 0, stream>>>(zh, zt, Whi, Wlo, pA);
    k_final_mfma<<<3200, 128, 0, stream>>>(pA, r96p, bb, out);
  } else {
    k_zht<<<dim3(200, 3, 2), 256, 0, stream>>>(ent_emb, rs, hts, Wh, bh, Wt, bt, zh, zt);
    k_logits_flat<<<1200, 256, 0, stream>>>(zh, zt, Wb, pA);
    k_final_flat<<<3200, 128, 0, stream>>>(pA, bb, out);
  }
}